// Round 7
// baseline (284.057 us; speedup 1.0000x reference)
//
#include <hip/hip_runtime.h>
#include <hip/hip_bf16.h>

#define EDGES  500000
#define NNODES 100000
#define QN     256
#define RN     401
#define DD     64
#define AA     64
#define OO     64
#define NB     391          // ceil(NNODES/256)
#define EB     1954         // ceil(EDGES/256)

typedef __attribute__((ext_vector_type(8))) short short8;
typedef __attribute__((ext_vector_type(4))) float f32x4;
typedef __attribute__((ext_vector_type(2))) float f32x2;

__device__ inline unsigned short f2bf(float f) {
    union { float f; unsigned int u; } v; v.f = f;
    unsigned int u = v.u;
    u += 0x7FFFu + ((u >> 16) & 1u);   // round-to-nearest-even
    return (unsigned short)(u >> 16);
}

// unpack two bf16 (packed in a u32, little-endian) to two fp32
__device__ inline f32x2 bfpair2f(unsigned int u) {
    union { unsigned int i; float f; } lo, hi;
    lo.i = u << 16;
    hi.i = u & 0xFFFF0000u;
    f32x2 r; r[0] = lo.f; r[1] = hi.f; return r;
}

__device__ inline short8 load8_cvt(const float* __restrict__ p) {
    f32x4 x0 = ((const f32x4*)p)[0];
    f32x4 x1 = ((const f32x4*)p)[1];
    short8 r;
    r[0] = (short)f2bf(x0[0]); r[1] = (short)f2bf(x0[1]);
    r[2] = (short)f2bf(x0[2]); r[3] = (short)f2bf(x0[3]);
    r[4] = (short)f2bf(x1[0]); r[5] = (short)f2bf(x1[1]);
    r[6] = (short)f2bf(x1[2]); r[7] = (short)f2bf(x1[3]);
    return r;
}

__device__ inline short8 load8_cvt_prod(const float* __restrict__ pa,
                                        const float* __restrict__ pb) {
    f32x4 a0 = ((const f32x4*)pa)[0];
    f32x4 a1 = ((const f32x4*)pa)[1];
    f32x4 b0 = ((const f32x4*)pb)[0];
    f32x4 b1 = ((const f32x4*)pb)[1];
    short8 r;
    r[0] = (short)f2bf(a0[0]*b0[0]); r[1] = (short)f2bf(a0[1]*b0[1]);
    r[2] = (short)f2bf(a0[2]*b0[2]); r[3] = (short)f2bf(a0[3]*b0[3]);
    r[4] = (short)f2bf(a1[0]*b1[0]); r[5] = (short)f2bf(a1[1]*b1[1]);
    r[6] = (short)f2bf(a1[2]*b1[2]); r[7] = (short)f2bf(a1[3]*b1[3]);
    return r;
}

// ---------------------------------------------------------------------------
// K1: Xs = hidden @ Ws^T (MFMA, K=64), bf16 out; also emits hidden_bf.
// ---------------------------------------------------------------------------
__global__ void k_xs(const float* __restrict__ hidden,
                     const float* __restrict__ Ws_W,
                     short* __restrict__ Xs,
                     short* __restrict__ hidden_bf) {
    __shared__ short W[AA * 72];
    int tid = threadIdx.x;
    for (int idx = tid; idx < AA * DD; idx += 256) {
        int a = idx >> 6, d = idx & 63;
        W[a * 72 + d] = (short)f2bf(Ws_W[idx]);
    }
    __syncthreads();
    int wave = tid >> 6, lane = tid & 63;
    int quad = lane >> 4, l15 = lane & 15;
    int rowbase = blockIdx.x * 64 + wave * 16;
    int row_a = rowbase + l15;

    f32x4 acc[4];
    for (int t = 0; t < 4; ++t) { acc[t][0]=acc[t][1]=acc[t][2]=acc[t][3]=0.f; }

#pragma unroll
    for (int ks = 0; ks < 2; ++ks) {
        int ka = ks * 32 + quad * 8;
        short8 afrag;
        if (row_a < NNODES) {
            afrag = load8_cvt(hidden + (size_t)row_a * DD + ka);
            *(short8*)(hidden_bf + (size_t)row_a * DD + ka) = afrag;
        } else {
            afrag = short8{0,0,0,0,0,0,0,0};
        }
#pragma unroll
        for (int t = 0; t < 4; ++t) {
            short8 bfrag = *(const short8*)&W[(t * 16 + l15) * 72 + ka];
            acc[t] = __builtin_amdgcn_mfma_f32_16x16x32_bf16(afrag, bfrag, acc[t], 0, 0, 0);
        }
    }
#pragma unroll
    for (int t = 0; t < 4; ++t)
#pragma unroll
        for (int r = 0; r < 4; ++r) {
            int row = rowbase + quad * 4 + r;
            if (row < NNODES) Xs[(size_t)row * AA + t * 16 + l15] = (short)f2bf(acc[t][r]);
        }
}

// ---------------------------------------------------------------------------
// K2: P = Ws_b + concat(hq,hr,hq*hr) @ concat(Wq,Wr,Wqr)^T  (K=192), bf16 out
// ---------------------------------------------------------------------------
__global__ void k_p(const float* __restrict__ q_emb,
                    const float* __restrict__ rela,
                    const float* __restrict__ Wq_W,
                    const float* __restrict__ Wr_W,
                    const float* __restrict__ Wqr_W,
                    const float* __restrict__ Ws_b,
                    short* __restrict__ P) {
    __shared__ short W[AA * 200];
    int tid = threadIdx.x;
    for (int idx = tid; idx < AA * 192; idx += 256) {
        int a = idx / 192, k = idx - a * 192;
        float v = (k < 64) ? Wq_W[a * 64 + k]
                : (k < 128) ? Wr_W[a * 64 + (k - 64)]
                            : Wqr_W[a * 64 + (k - 128)];
        W[a * 200 + k] = (short)f2bf(v);
    }
    __syncthreads();
    int wave = tid >> 6, lane = tid & 63;
    int quad = lane >> 4, l15 = lane & 15;
    int pairbase = blockIdx.x * 64 + wave * 16;
    int mypair = pairbase + l15;
    int q = mypair / RN;
    int r = mypair - q * RN;
    const float* hq = q_emb + (size_t)q * DD;
    const float* hr = rela  + (size_t)r * DD;

    f32x4 acc[4];
#pragma unroll
    for (int t = 0; t < 4; ++t) {
        float b = Ws_b[t * 16 + l15];
        acc[t][0] = acc[t][1] = acc[t][2] = acc[t][3] = b;
    }

#pragma unroll
    for (int ks = 0; ks < 6; ++ks) {
        int ka = ks * 32 + quad * 8;
        short8 afrag;
        if (ka < 64)       afrag = load8_cvt(hq + ka);
        else if (ka < 128) afrag = load8_cvt(hr + (ka - 64));
        else               afrag = load8_cvt_prod(hq + (ka - 128), hr + (ka - 128));
#pragma unroll
        for (int t = 0; t < 4; ++t) {
            short8 bfrag = *(const short8*)&W[(t * 16 + l15) * 200 + ka];
            acc[t] = __builtin_amdgcn_mfma_f32_16x16x32_bf16(afrag, bfrag, acc[t], 0, 0, 0);
        }
    }
#pragma unroll
    for (int t = 0; t < 4; ++t)
#pragma unroll
        for (int rg = 0; rg < 4; ++rg) {
            int row = pairbase + quad * 4 + rg;
            P[(size_t)row * AA + t * 16 + l15] = (short)f2bf(acc[t][rg]);
        }
}

// ---------------------------------------------------------------------------
// Sort by obj: histogram -> 2-level exclusive scan -> scatter edge ids
// ---------------------------------------------------------------------------
__global__ void s1_hist(const int* __restrict__ edges, unsigned* __restrict__ cnt) {
    int e = blockIdx.x * 256 + threadIdx.x;
    if (e < EDGES) atomicAdd(&cnt[edges[(size_t)e * 6 + 5]], 1u);
}

__global__ void s2a_scan(const unsigned* __restrict__ cnt,
                         unsigned* __restrict__ start_local,
                         unsigned* __restrict__ cursor,
                         unsigned* __restrict__ bsum) {
    __shared__ unsigned sm[256];
    int t = threadIdx.x;
    int i = blockIdx.x * 256 + t;
    unsigned v = (i < NNODES) ? cnt[i] : 0u;
    sm[t] = v;
    __syncthreads();
    for (int off = 1; off < 256; off <<= 1) {
        unsigned u = (t >= off) ? sm[t - off] : 0u;
        __syncthreads();
        sm[t] += u;
        __syncthreads();
    }
    unsigned excl = sm[t] - v;
    if (i < NNODES) { start_local[i] = excl; cursor[i] = excl; }
    if (t == 255) bsum[blockIdx.x] = sm[255];
}

__global__ void s2b_scan(unsigned* __restrict__ bsum) {
    __shared__ unsigned sm[512];
    int t = threadIdx.x;
    unsigned v = (t < NB) ? bsum[t] : 0u;
    sm[t] = v;
    __syncthreads();
    for (int off = 1; off < 512; off <<= 1) {
        unsigned u = (t >= off) ? sm[t - off] : 0u;
        __syncthreads();
        sm[t] += u;
        __syncthreads();
    }
    if (t < NB) bsum[t] = sm[t] - v;   // exclusive prefix of block sums
}

__global__ void s3_scatter(const int* __restrict__ edges,
                           unsigned* __restrict__ cursor,
                           const unsigned* __restrict__ bsum,
                           unsigned* __restrict__ sorted_eid) {
    int e = blockIdx.x * 256 + threadIdx.x;
    if (e >= EDGES) return;
    int obj = edges[(size_t)e * 6 + 5];
    unsigned p = atomicAdd(&cursor[obj], 1u) + bsum[obj >> 8];
    sorted_eid[p] = (unsigned)e;
}

// ---------------------------------------------------------------------------
// K3: atomic-free aggregation. One half-wave (32 lanes) per node: loop the
// node's CSR segment, compute alpha inline, fp32-accumulate, write row once.
// ---------------------------------------------------------------------------
__global__ void k_agg(const unsigned* __restrict__ sorted_eid,
                      const unsigned* __restrict__ start_local,
                      const unsigned* __restrict__ bsum,
                      const unsigned* __restrict__ cnt,
                      const int* __restrict__ edges,
                      const short* __restrict__ Xs,
                      const short* __restrict__ P,
                      const short* __restrict__ hidden_bf,
                      const float* __restrict__ rela,
                      const float* __restrict__ wa_W,
                      const float* __restrict__ wa_b,
                      short* __restrict__ agg,
                      float* __restrict__ alpha_out) {
    int tid = threadIdx.x;
    int l32 = tid & 31;
    int n = blockIdx.x * 8 + (tid >> 5);
    int c2 = 2 * l32;
    unsigned base = start_local[n] + bsum[n >> 8];
    unsigned num = cnt[n];
    float wab = wa_b[0];
    f32x2 wa = *(const f32x2*)&wa_W[c2];
    float a0 = 0.f, a1 = 0.f;
    for (unsigned j = 0; j < num; ++j) {
        unsigned e = sorted_eid[base + j];
        const int* ep = edges + (size_t)e * 6;
        int q = ep[0], r = ep[2], sub = ep[4];
        unsigned xs_u = *(const unsigned*)&Xs[(size_t)sub * AA + c2];
        unsigned pp_u = *(const unsigned*)&P[((size_t)q * RN + r) * AA + c2];
        f32x2 xs = bfpair2f(xs_u), pp = bfpair2f(pp_u);
        float v = fmaxf(xs[0] + pp[0], 0.f) * wa[0]
                + fmaxf(xs[1] + pp[1], 0.f) * wa[1];
#pragma unroll
        for (int off = 16; off > 0; off >>= 1) v += __shfl_xor(v, off, 64); // stays in half
        float alpha = 1.f / (1.f + __expf(-(v + wab)));
        if (l32 == 0) alpha_out[e] = alpha;
        unsigned hs_u = *(const unsigned*)&hidden_bf[(size_t)sub * DD + c2];
        f32x2 hs = bfpair2f(hs_u);
        f32x2 hr = *(const f32x2*)&rela[(size_t)r * DD + c2];
        a0 += alpha * hs[0] * hr[0];
        a1 += alpha * hs[1] * hr[1];
    }
    unsigned packed = (unsigned)(unsigned short)f2bf(a0)
                    | ((unsigned)f2bf(a1) << 16);
    *(unsigned*)&agg[(size_t)n * DD + c2] = packed;
}

// ---------------------------------------------------------------------------
// K4: hidden_new = agg @ Wh^T   (MFMA, K=64; agg bf16)
// ---------------------------------------------------------------------------
__global__ void k_out(const short* __restrict__ agg,
                      const float* __restrict__ Wh_W,
                      float* __restrict__ out) {
    __shared__ short W[OO * 72];
    int tid = threadIdx.x;
    for (int idx = tid; idx < OO * DD; idx += 256) {
        int o = idx >> 6, d = idx & 63;
        W[o * 72 + d] = (short)f2bf(Wh_W[idx]);
    }
    __syncthreads();
    int wave = tid >> 6, lane = tid & 63;
    int quad = lane >> 4, l15 = lane & 15;
    int rowbase = blockIdx.x * 64 + wave * 16;
    int row_a = rowbase + l15;

    f32x4 acc[4];
    for (int t = 0; t < 4; ++t) { acc[t][0]=acc[t][1]=acc[t][2]=acc[t][3]=0.f; }

#pragma unroll
    for (int ks = 0; ks < 2; ++ks) {
        int ka = ks * 32 + quad * 8;
        short8 afrag;
        if (row_a < NNODES) afrag = *(const short8*)(agg + (size_t)row_a * DD + ka);
        else                afrag = short8{0,0,0,0,0,0,0,0};
#pragma unroll
        for (int t = 0; t < 4; ++t) {
            short8 bfrag = *(const short8*)&W[(t * 16 + l15) * 72 + ka];
            acc[t] = __builtin_amdgcn_mfma_f32_16x16x32_bf16(afrag, bfrag, acc[t], 0, 0, 0);
        }
    }
#pragma unroll
    for (int t = 0; t < 4; ++t)
#pragma unroll
        for (int r = 0; r < 4; ++r) {
            int row = rowbase + quad * 4 + r;
            if (row < NNODES) out[(size_t)row * OO + t * 16 + l15] = acc[t][r];
        }
}

// ---------------------------------------------------------------------------
extern "C" void kernel_launch(void* const* d_in, const int* in_sizes, int n_in,
                              void* d_out, int out_size, void* d_ws, size_t ws_size,
                              hipStream_t stream) {
    const float* q_emb  = (const float*)d_in[1];
    const float* rela   = (const float*)d_in[2];
    const float* hidden = (const float*)d_in[3];
    const int*   edges  = (const int*)d_in[4];
    const float* Ws_W   = (const float*)d_in[6];
    const float* Ws_b   = (const float*)d_in[7];
    const float* Wr_W   = (const float*)d_in[8];
    const float* Wq_W   = (const float*)d_in[9];
    const float* Wqr_W  = (const float*)d_in[10];
    const float* wa_W   = (const float*)d_in[11];
    const float* wa_b   = (const float*)d_in[12];
    const float* Wh_W   = (const float*)d_in[13];

    // workspace layout
    short* Xs        = (short*)d_ws;                         // N*A   bf16
    short* P         = Xs + (size_t)NNODES * AA;             // Q*R*A bf16
    short* hidden_bf = P + (size_t)QN * RN * AA;             // N*D   bf16
    short* agg       = hidden_bf + (size_t)NNODES * DD;      // N*D   bf16
    unsigned* cnt         = (unsigned*)(agg + (size_t)NNODES * DD);
    unsigned* start_local = cnt + NNODES;
    unsigned* cursor      = start_local + NNODES;
    unsigned* bsum        = cursor + NNODES;                 // NB entries
    unsigned* sorted_eid  = bsum + 512;                      // E entries

    float* out       = (float*)d_out;                        // hidden_new (N*O)
    float* alpha_out = out + (size_t)NNODES * OO;            // alpha (E)

    (void)hipMemsetAsync(cnt, 0, (size_t)NNODES * sizeof(unsigned), stream);

    s1_hist   <<<EB, 256, 0, stream>>>(edges, cnt);
    s2a_scan  <<<NB, 256, 0, stream>>>(cnt, start_local, cursor, bsum);
    s2b_scan  <<<1, 512, 0, stream>>>(bsum);
    s3_scatter<<<EB, 256, 0, stream>>>(edges, cursor, bsum, sorted_eid);

    k_xs<<<(NNODES + 63) / 64, 256, 0, stream>>>(hidden, Ws_W, Xs, hidden_bf);
    k_p <<<(QN * RN) / 64, 256, 0, stream>>>(q_emb, rela, Wq_W, Wr_W, Wqr_W, Ws_b, P);

    k_agg<<<NNODES / 8, 256, 0, stream>>>(sorted_eid, start_local, bsum, cnt, edges,
                                          Xs, P, hidden_bf, rela, wa_W, wa_b,
                                          agg, alpha_out);
    k_out<<<(NNODES + 63) / 64, 256, 0, stream>>>(agg, Wh_W, out);
}

// Round 8
// 205.166 us; speedup vs baseline: 1.3845x; 1.3845x over previous
//
#include <hip/hip_runtime.h>
#include <hip/hip_bf16.h>

#define EDGES  500000
#define NNODES 100000
#define QN     256
#define RN     401
#define DD     64
#define AA     64
#define OO     64
#define XSB    1563      // ceil(NNODES/64) blocks for xs-phase
#define PB     1604      // (QN*RN)/64 blocks for p-phase (exact)

typedef __attribute__((ext_vector_type(8))) short short8;
typedef __attribute__((ext_vector_type(2))) short short2v;
typedef __attribute__((ext_vector_type(4))) float f32x4;
typedef __attribute__((ext_vector_type(2))) float f32x2;

__device__ inline unsigned short f2bf(float f) {
    union { float f; unsigned int u; } v; v.f = f;
    unsigned int u = v.u;
    u += 0x7FFFu + ((u >> 16) & 1u);   // round-to-nearest-even
    return (unsigned short)(u >> 16);
}

// unpack two bf16 (packed in a u32, little-endian) to two fp32
__device__ inline f32x2 bfpair2f(unsigned int u) {
    union { unsigned int i; float f; } lo, hi;
    lo.i = u << 16;
    hi.i = u & 0xFFFF0000u;
    f32x2 r; r[0] = lo.f; r[1] = hi.f; return r;
}

__device__ inline short8 load8_cvt(const float* __restrict__ p) {
    f32x4 x0 = ((const f32x4*)p)[0];
    f32x4 x1 = ((const f32x4*)p)[1];
    short8 r;
    r[0] = (short)f2bf(x0[0]); r[1] = (short)f2bf(x0[1]);
    r[2] = (short)f2bf(x0[2]); r[3] = (short)f2bf(x0[3]);
    r[4] = (short)f2bf(x1[0]); r[5] = (short)f2bf(x1[1]);
    r[6] = (short)f2bf(x1[2]); r[7] = (short)f2bf(x1[3]);
    return r;
}

__device__ inline short8 load8_cvt_prod(const float* __restrict__ pa,
                                        const float* __restrict__ pb) {
    f32x4 a0 = ((const f32x4*)pa)[0];
    f32x4 a1 = ((const f32x4*)pa)[1];
    f32x4 b0 = ((const f32x4*)pb)[0];
    f32x4 b1 = ((const f32x4*)pb)[1];
    short8 r;
    r[0] = (short)f2bf(a0[0]*b0[0]); r[1] = (short)f2bf(a0[1]*b0[1]);
    r[2] = (short)f2bf(a0[2]*b0[2]); r[3] = (short)f2bf(a0[3]*b0[3]);
    r[4] = (short)f2bf(a1[0]*b1[0]); r[5] = (short)f2bf(a1[1]*b1[1]);
    r[6] = (short)f2bf(a1[2]*b1[2]); r[7] = (short)f2bf(a1[3]*b1[3]);
    return r;
}

// packed bf16x2 atomic add (global_atomic_pk_add_bf16, gfx90a+/CDNA4)
__device__ inline void atomic_pk_add_bf16(short* addr, short2v v) {
#if __has_builtin(__builtin_amdgcn_global_atomic_fadd_v2bf16)
    __builtin_amdgcn_global_atomic_fadd_v2bf16(
        (__attribute__((address_space(1))) short2v*)addr, v);
#else
    asm volatile("global_atomic_pk_add_bf16 %0, %1, off"
                 :: "v"(addr), "v"(v) : "memory");
#endif
}

// ---------------------------------------------------------------------------
// K_PRE: fused. Blocks [0,XSB): Xs = hidden @ Ws^T + emit hidden_bf + zero agg.
//        Blocks [XSB,XSB+PB): P = Ws_b + concat(hq,hr,hq*hr) @ W3^T (K=192).
// ---------------------------------------------------------------------------
__global__ void k_pre(const float* __restrict__ hidden,
                      const float* __restrict__ Ws_W,
                      const float* __restrict__ q_emb,
                      const float* __restrict__ rela,
                      const float* __restrict__ Wq_W,
                      const float* __restrict__ Wr_W,
                      const float* __restrict__ Wqr_W,
                      const float* __restrict__ Ws_b,
                      short* __restrict__ Xs,
                      short* __restrict__ hidden_bf,
                      short* __restrict__ P,
                      short* __restrict__ agg) {
    __shared__ short W[AA * 200];           // p-phase needs 200-stride; xs uses 72
    int tid = threadIdx.x;
    int wave = tid >> 6, lane = tid & 63;
    int quad = lane >> 4, l15 = lane & 15;

    if (blockIdx.x < XSB) {
        // ---------------- xs phase ----------------
        // zero agg rows owned by this block (before sync; independent of LDS)
        int rowbase_blk = blockIdx.x * 64;
        {
            const short8 z = short8{0,0,0,0,0,0,0,0};
            // 64 rows * 64 shorts = 4096 shorts; 256 threads * 2 short8 each
            int base = rowbase_blk * DD + tid * 16;
            int row0 = rowbase_blk + (tid * 16) / DD;    // = rowbase + tid/4
            if (row0 < NNODES) {
                *(short8*)(agg + base) = z;
                *(short8*)(agg + base + 8) = z;
            }
        }
        for (int idx = tid; idx < AA * DD; idx += 256) {
            int a = idx >> 6, d = idx & 63;
            W[a * 72 + d] = (short)f2bf(Ws_W[idx]);
        }
        __syncthreads();
        int rowbase = rowbase_blk + wave * 16;
        int row_a = rowbase + l15;

        f32x4 acc[4];
        for (int t = 0; t < 4; ++t) { acc[t][0]=acc[t][1]=acc[t][2]=acc[t][3]=0.f; }

#pragma unroll
        for (int ks = 0; ks < 2; ++ks) {
            int ka = ks * 32 + quad * 8;
            short8 afrag;
            if (row_a < NNODES) {
                afrag = load8_cvt(hidden + (size_t)row_a * DD + ka);
                *(short8*)(hidden_bf + (size_t)row_a * DD + ka) = afrag;
            } else {
                afrag = short8{0,0,0,0,0,0,0,0};
            }
#pragma unroll
            for (int t = 0; t < 4; ++t) {
                short8 bfrag = *(const short8*)&W[(t * 16 + l15) * 72 + ka];
                acc[t] = __builtin_amdgcn_mfma_f32_16x16x32_bf16(afrag, bfrag, acc[t], 0, 0, 0);
            }
        }
#pragma unroll
        for (int t = 0; t < 4; ++t)
#pragma unroll
            for (int r = 0; r < 4; ++r) {
                int row = rowbase + quad * 4 + r;
                if (row < NNODES) Xs[(size_t)row * AA + t * 16 + l15] = (short)f2bf(acc[t][r]);
            }
    } else {
        // ---------------- p phase ----------------
        int pb = blockIdx.x - XSB;
        for (int idx = tid; idx < AA * 192; idx += 256) {
            int a = idx / 192, k = idx - a * 192;
            float v = (k < 64) ? Wq_W[a * 64 + k]
                    : (k < 128) ? Wr_W[a * 64 + (k - 64)]
                                : Wqr_W[a * 64 + (k - 128)];
            W[a * 200 + k] = (short)f2bf(v);
        }
        __syncthreads();
        int pairbase = pb * 64 + wave * 16;
        int mypair = pairbase + l15;
        int q = mypair / RN;
        int r = mypair - q * RN;
        const float* hq = q_emb + (size_t)q * DD;
        const float* hr = rela  + (size_t)r * DD;

        f32x4 acc[4];
#pragma unroll
        for (int t = 0; t < 4; ++t) {
            float b = Ws_b[t * 16 + l15];
            acc[t][0] = acc[t][1] = acc[t][2] = acc[t][3] = b;
        }

#pragma unroll
        for (int ks = 0; ks < 6; ++ks) {
            int ka = ks * 32 + quad * 8;
            short8 afrag;
            if (ka < 64)       afrag = load8_cvt(hq + ka);
            else if (ka < 128) afrag = load8_cvt(hr + (ka - 64));
            else               afrag = load8_cvt_prod(hq + (ka - 128), hr + (ka - 128));
#pragma unroll
            for (int t = 0; t < 4; ++t) {
                short8 bfrag = *(const short8*)&W[(t * 16 + l15) * 200 + ka];
                acc[t] = __builtin_amdgcn_mfma_f32_16x16x32_bf16(afrag, bfrag, acc[t], 0, 0, 0);
            }
        }
#pragma unroll
        for (int t = 0; t < 4; ++t)
#pragma unroll
            for (int rg = 0; rg < 4; ++rg) {
                int row = pairbase + quad * 4 + rg;
                P[(size_t)row * AA + t * 16 + l15] = (short)f2bf(acc[t][rg]);
            }
    }
}

// ---------------------------------------------------------------------------
// K3: 2 edges per wave (32 lanes / edge, bf16x2 per lane), bf16 pk atomics.
// ---------------------------------------------------------------------------
__global__ void k_edge(const int* __restrict__ edges,
                       const short* __restrict__ Xs,
                       const short* __restrict__ P,
                       const short* __restrict__ hidden_bf,
                       const float* __restrict__ rela,
                       const float* __restrict__ wa_W,
                       const float* __restrict__ wa_b,
                       short* __restrict__ agg,
                       float* __restrict__ alpha_out) {
    int tid  = threadIdx.x;
    int wave = tid >> 6, lane = tid & 63;
    int l32  = lane & 31;
    int half = lane >> 5;
    size_t e = (size_t)blockIdx.x * 8 + wave * 2 + half;

    const int* ep = edges + e * 6;
    int q = ep[0];
    int r = ep[2];
    int2 so = *(const int2*)&ep[4];          // {sub, obj}
    int sub = so.x, obj = so.y;

    int c2 = 2 * l32;
    unsigned int xs_u = *(const unsigned int*)&Xs[(size_t)sub * AA + c2];
    unsigned int pp_u = *(const unsigned int*)&P[((size_t)q * RN + r) * AA + c2];
    f32x2 xs = bfpair2f(xs_u);
    f32x2 pp = bfpair2f(pp_u);
    f32x2 wa = *(const f32x2*)&wa_W[c2];

    float v = fmaxf(xs[0] + pp[0], 0.f) * wa[0]
            + fmaxf(xs[1] + pp[1], 0.f) * wa[1];
#pragma unroll
    for (int off = 16; off > 0; off >>= 1) v += __shfl_xor(v, off, 64); // stays in half
    float alpha = 1.f / (1.f + __expf(-(v + wa_b[0])));
    if (l32 == 0) alpha_out[e] = alpha;

    unsigned int hs_u = *(const unsigned int*)&hidden_bf[(size_t)sub * DD + c2];
    f32x2 hs = bfpair2f(hs_u);
    f32x2 hr = *(const f32x2*)&rela[(size_t)r * DD + c2];
    short2v m;
    m[0] = (short)f2bf(alpha * hs[0] * hr[0]);
    m[1] = (short)f2bf(alpha * hs[1] * hr[1]);
    atomic_pk_add_bf16((short*)agg + (size_t)obj * DD + c2, m);
}

// ---------------------------------------------------------------------------
// K4: hidden_new = agg @ Wh^T   (MFMA, K=64; agg bf16)
// ---------------------------------------------------------------------------
__global__ void k_out(const short* __restrict__ agg,
                      const float* __restrict__ Wh_W,
                      float* __restrict__ out) {
    __shared__ short W[OO * 72];
    int tid = threadIdx.x;
    for (int idx = tid; idx < OO * DD; idx += 256) {
        int o = idx >> 6, d = idx & 63;
        W[o * 72 + d] = (short)f2bf(Wh_W[idx]);
    }
    __syncthreads();
    int wave = tid >> 6, lane = tid & 63;
    int quad = lane >> 4, l15 = lane & 15;
    int rowbase = blockIdx.x * 64 + wave * 16;
    int row_a = rowbase + l15;

    f32x4 acc[4];
    for (int t = 0; t < 4; ++t) { acc[t][0]=acc[t][1]=acc[t][2]=acc[t][3]=0.f; }

#pragma unroll
    for (int ks = 0; ks < 2; ++ks) {
        int ka = ks * 32 + quad * 8;
        short8 afrag;
        if (row_a < NNODES) afrag = *(const short8*)(agg + (size_t)row_a * DD + ka);
        else                afrag = short8{0,0,0,0,0,0,0,0};
#pragma unroll
        for (int t = 0; t < 4; ++t) {
            short8 bfrag = *(const short8*)&W[(t * 16 + l15) * 72 + ka];
            acc[t] = __builtin_amdgcn_mfma_f32_16x16x32_bf16(afrag, bfrag, acc[t], 0, 0, 0);
        }
    }
#pragma unroll
    for (int t = 0; t < 4; ++t)
#pragma unroll
        for (int r = 0; r < 4; ++r) {
            int row = rowbase + quad * 4 + r;
            if (row < NNODES) out[(size_t)row * OO + t * 16 + l15] = acc[t][r];
        }
}

// ---------------------------------------------------------------------------
extern "C" void kernel_launch(void* const* d_in, const int* in_sizes, int n_in,
                              void* d_out, int out_size, void* d_ws, size_t ws_size,
                              hipStream_t stream) {
    const float* q_emb  = (const float*)d_in[1];
    const float* rela   = (const float*)d_in[2];
    const float* hidden = (const float*)d_in[3];
    const int*   edges  = (const int*)d_in[4];
    const float* Ws_W   = (const float*)d_in[6];
    const float* Ws_b   = (const float*)d_in[7];
    const float* Wr_W   = (const float*)d_in[8];
    const float* Wq_W   = (const float*)d_in[9];
    const float* Wqr_W  = (const float*)d_in[10];
    const float* wa_W   = (const float*)d_in[11];
    const float* wa_b   = (const float*)d_in[12];
    const float* Wh_W   = (const float*)d_in[13];

    // workspace layout (bf16 shorts)
    short* Xs        = (short*)d_ws;                         // N*A
    short* P         = Xs + (size_t)NNODES * AA;             // Q*R*A
    short* hidden_bf = P + (size_t)QN * RN * AA;             // N*D
    short* agg       = hidden_bf + (size_t)NNODES * DD;      // N*D

    float* out       = (float*)d_out;                        // hidden_new (N*O)
    float* alpha_out = out + (size_t)NNODES * OO;            // alpha (E)

    k_pre<<<XSB + PB, 256, 0, stream>>>(hidden, Ws_W, q_emb, rela,
                                        Wq_W, Wr_W, Wqr_W, Ws_b,
                                        Xs, hidden_bf, P, agg);
    k_edge<<<EDGES / 8, 256, 0, stream>>>(edges, Xs, P, hidden_bf, rela, wa_W, wa_b,
                                          agg, alpha_out);
    k_out<<<(NNODES + 63) / 64, 256, 0, stream>>>(agg, Wh_W, out);
}